// Round 1
// baseline (616.150 us; speedup 1.0000x reference)
//
#include <hip/hip_runtime.h>
#include <hip/hip_bf16.h>
#include <math.h>

#define N_NODES 50000
#define N_EDGES 800000
#define GK 256

typedef unsigned short US;
typedef __attribute__((ext_vector_type(8))) short short8;
typedef __attribute__((ext_vector_type(4))) float floatx4;
typedef __attribute__((address_space(1))) const void* gptr_t;
typedef __attribute__((address_space(3))) void* lptr_t;

static __device__ __forceinline__ float bflo(unsigned int u) {
  union { unsigned int i; float f; } c; c.i = u << 16; return c.f;
}
static __device__ __forceinline__ float bfhi(unsigned int u) {
  union { unsigned int i; float f; } c; c.i = u & 0xffff0000u; return c.f;
}
static __device__ __forceinline__ float bf2f(US u) {
  union { unsigned int i; float f; } c; c.i = ((unsigned int)u) << 16; return c.f;
}
static __device__ __forceinline__ US f2bf(float f) {  // round-to-nearest-even
  union { float f; unsigned int i; } c; c.f = f;
  unsigned int x = c.i;
  return (US)((x + 0x7fffu + ((x >> 16) & 1u)) >> 16);
}

// ----------------- preprocessing -----------------

// fused: in-degree histogram + x->bf16 + all weight transposes
__global__ void pre0_kernel(const int* __restrict__ col, int* __restrict__ cnt,
                            const float* __restrict__ x, US* __restrict__ xb,
                            const float* __restrict__ W1, const float* __restrict__ W2,
                            const float* __restrict__ W3, const float* __restrict__ W4,
                            US* __restrict__ Wt1, US* __restrict__ Wt2,
                            US* __restrict__ Wt3, US* __restrict__ Wt4) {
  int gt = blockIdx.x * 256 + threadIdx.x;
  int gs = gridDim.x * 256;
  for (int e = gt; e < N_EDGES; e += gs) atomicAdd(&cnt[col[e]], 1);
  for (int i = gt; i < N_NODES * 64; i += gs) {   // x: 12.8M elems / 4
    float4 v = *(const float4*)(x + (size_t)i * 4);
    US o[4] = { f2bf(v.x), f2bf(v.y), f2bf(v.z), f2bf(v.w) };
    *(ushort4*)(xb + (size_t)i * 4) = *(ushort4*)o;
  }
  for (int idx = gt; idx < 151552; idx += gs) {
    if (idx < 65536) {
      int k = idx >> 8, n = idx & 255;
      Wt1[n * 256 + k] = f2bf(W1[idx]);
    } else if (idx < 131072) {
      int i = idx - 65536, k = i >> 8, n = i & 255;
      Wt2[n * 256 + k] = f2bf(W2[i]);
    } else if (idx < 147456) {
      int i = idx - 131072, k = i >> 6, n = i & 63;
      Wt3[n * 256 + k] = f2bf(W3[i]);
    } else {
      int i = idx - 147456, k = i >> 6, n = i & 63;
      Wt4[n * 64 + k] = f2bf(W4[i]);
    }
  }
}

__global__ void scan_block_kernel(const int* __restrict__ in, int* __restrict__ out,
                                  int* __restrict__ bsums, float* __restrict__ dinv, int n) {
  __shared__ int s[256];
  int gid = blockIdx.x * 256 + threadIdx.x;
  int v = (gid < n) ? in[gid] : 0;
  if (gid < n) dinv[gid] = 1.0f / sqrtf((float)(v + 1));  // +1 self-loop
  s[threadIdx.x] = v;
  __syncthreads();
  for (int off = 1; off < 256; off <<= 1) {
    int t = (threadIdx.x >= off) ? s[threadIdx.x - off] : 0;
    __syncthreads();
    s[threadIdx.x] += t;
    __syncthreads();
  }
  if (gid < n) out[gid] = s[threadIdx.x] - v;  // exclusive
  if (threadIdx.x == 255) bsums[blockIdx.x] = s[255];
}

__global__ void scan_top_kernel(int* __restrict__ bsums, int n) {
  __shared__ int s[256];
  int v = (threadIdx.x < n) ? bsums[threadIdx.x] : 0;
  s[threadIdx.x] = v;
  __syncthreads();
  for (int off = 1; off < 256; off <<= 1) {
    int t = (threadIdx.x >= off) ? s[threadIdx.x - off] : 0;
    __syncthreads();
    s[threadIdx.x] += t;
    __syncthreads();
  }
  if (threadIdx.x < n) bsums[threadIdx.x] = s[threadIdx.x] - v;
}

__global__ void scan_add_kernel(int* __restrict__ row_ptr, int* __restrict__ fill,
                                const int* __restrict__ bsums, int n) {
  int gid = blockIdx.x * 256 + threadIdx.x;
  if (gid < n) {
    int v = row_ptr[gid] + bsums[blockIdx.x];
    row_ptr[gid] = v;
    fill[gid] = v;
  }
}

__global__ void fill_kernel(const int* __restrict__ row, const int* __restrict__ col,
                            int* __restrict__ fill, int2* __restrict__ srcs2,
                            const float* __restrict__ dinv, int E) {
  int e = blockIdx.x * blockDim.x + threadIdx.x;
  if (e < E) {
    int d = col[e];
    int r = row[e];
    int pos = atomicAdd(&fill[d], 1);
    srcs2[pos] = make_int2(r, __float_as_int(dinv[r]));
  }
}

// ----------------- gemm256: C[M,256] = A[M,256] @ Wt[256,256]^T -----------------
// M-tile 64, 4 waves = 64-col quadrants, BK=64, global_load_lds 16B, XOR swizzle.
// Epilogue: C-tile staged in LDS (pad +16 cols) -> 16B/lane coalesced stores.

__global__ __launch_bounds__(256) void gemm256_kernel(
    const US* __restrict__ A, const US* __restrict__ Wt,
    US* __restrict__ C, int M) {
  __shared__ __align__(16) US shm[20480];     // 40 KB: staging (As+Bs) / C-tile
  US* As = shm;                                // 64x64   = 4096 US
  US* Bs = shm + 4096;                         // 256x64  = 16384 US
  int tid = threadIdx.x;
  int bm = blockIdx.x * 64;
  int lane = tid & 63;
  int w = tid >> 6;
  int wc = w * 64;
  int lm = lane & 15, lk = lane >> 4;
  int lr = lane >> 3, lc = lane & 7;
  int gc = lc ^ lr;

  floatx4 zero = {0.f, 0.f, 0.f, 0.f};
  floatx4 acc[4][4];
#pragma unroll
  for (int i = 0; i < 4; ++i)
#pragma unroll
    for (int j = 0; j < 4; ++j) acc[i][j] = zero;

  for (int k0 = 0; k0 < GK; k0 += 64) {
#pragma unroll
    for (int i = 0; i < 2; ++i) {
      int rbase = i * 32 + w * 8;
      int r = rbase + lr;
      const US* ga = A + (size_t)(bm + r) * GK + k0 + gc * 8;
      lptr_t la = (lptr_t)(void*)&As[rbase * 64];
      if (bm + r < M)
        __builtin_amdgcn_global_load_lds((gptr_t)(const void*)ga, la, 16, 0, 0);
    }
#pragma unroll
    for (int i = 0; i < 8; ++i) {
      int rbase = i * 32 + w * 8;
      int r = rbase + lr;
      const US* gb = Wt + (size_t)r * GK + k0 + gc * 8;
      lptr_t lb = (lptr_t)(void*)&Bs[rbase * 64];
      __builtin_amdgcn_global_load_lds((gptr_t)(const void*)gb, lb, 16, 0, 0);
    }
    __syncthreads();
#pragma unroll
    for (int s = 0; s < 2; ++s) {
      short8 af[4], bfr[4];
#pragma unroll
      for (int i = 0; i < 4; ++i) {
        int row = i * 16 + lm;
        int c = (s * 4 + lk) ^ (row & 7);
        af[i] = *(const short8*)&As[row * 64 + c * 8];
      }
#pragma unroll
      for (int j = 0; j < 4; ++j) {
        int row = wc + j * 16 + lm;
        int c = (s * 4 + lk) ^ (row & 7);
        bfr[j] = *(const short8*)&Bs[row * 64 + c * 8];
      }
#pragma unroll
      for (int i = 0; i < 4; ++i)
#pragma unroll
        for (int j = 0; j < 4; ++j)
          acc[i][j] = __builtin_amdgcn_mfma_f32_16x16x32_bf16(af[i], bfr[j], acc[i][j], 0, 0, 0);
    }
    __syncthreads();
  }

  // epilogue: LDS stage (64 rows x 256 cols, pad 16) -> coalesced 16B stores
  {
    constexpr int LDC = 272;
    US* Cs = shm;                              // 64*272 = 17408 US <= 20480
#pragma unroll
    for (int i = 0; i < 4; ++i)
#pragma unroll
      for (int j = 0; j < 4; ++j) {
        int colg = wc + j * 16 + lm;
#pragma unroll
        for (int r = 0; r < 4; ++r)
          Cs[(i * 16 + lk * 4 + r) * LDC + colg] = f2bf(acc[i][j][r]);
      }
    __syncthreads();
#pragma unroll
    for (int c = 0; c < 8; ++c) {              // 2048 = 64 rows x 32 chunks
      int idx = tid + c * 256;
      int row = idx >> 5;
      int ch = idx & 31;
      uint4 v = *(const uint4*)&Cs[row * LDC + ch * 8];
      if (bm + row < M) *(uint4*)&C[(size_t)(bm + row) * 256 + ch * 8] = v;
    }
  }
}

// ----------------- gemm64: C[M,64] = A[M,256] @ Wt3[64,256]^T -----------------

__global__ __launch_bounds__(256) void gemm64_kernel(
    const US* __restrict__ A, const US* __restrict__ Wt,
    US* __restrict__ C, int M) {
  __shared__ __align__(16) US shm[12288];     // 24 KB staging / C-tile
  US* As = shm;                                // 128x64 = 8192 US
  US* Bs = shm + 8192;                         // 64x64  = 4096 US
  int tid = threadIdx.x;
  int bm = blockIdx.x * 128;
  int lane = tid & 63;
  int w = tid >> 6;
  int wr = w * 32;
  int lm = lane & 15, lk = lane >> 4;
  int lr = lane >> 3, lc = lane & 7;
  int gc = lc ^ lr;

  floatx4 zero = {0.f, 0.f, 0.f, 0.f};
  floatx4 acc[2][4];
#pragma unroll
  for (int i = 0; i < 2; ++i)
#pragma unroll
    for (int j = 0; j < 4; ++j) acc[i][j] = zero;

  for (int k0 = 0; k0 < GK; k0 += 64) {
#pragma unroll
    for (int i = 0; i < 4; ++i) {
      int rbase = i * 32 + w * 8;
      int r = rbase + lr;
      const US* ga = A + (size_t)(bm + r) * GK + k0 + gc * 8;
      lptr_t la = (lptr_t)(void*)&As[rbase * 64];
      if (bm + r < M)
        __builtin_amdgcn_global_load_lds((gptr_t)(const void*)ga, la, 16, 0, 0);
    }
#pragma unroll
    for (int i = 0; i < 2; ++i) {
      int rbase = i * 32 + w * 8;
      int r = rbase + lr;
      const US* gb = Wt + (size_t)r * GK + k0 + gc * 8;
      lptr_t lb = (lptr_t)(void*)&Bs[rbase * 64];
      __builtin_amdgcn_global_load_lds((gptr_t)(const void*)gb, lb, 16, 0, 0);
    }
    __syncthreads();
#pragma unroll
    for (int s = 0; s < 2; ++s) {
      short8 af[2], bfr[4];
#pragma unroll
      for (int i = 0; i < 2; ++i) {
        int row = wr + i * 16 + lm;
        int c = (s * 4 + lk) ^ (row & 7);
        af[i] = *(const short8*)&As[row * 64 + c * 8];
      }
#pragma unroll
      for (int j = 0; j < 4; ++j) {
        int row = j * 16 + lm;
        int c = (s * 4 + lk) ^ (row & 7);
        bfr[j] = *(const short8*)&Bs[row * 64 + c * 8];
      }
#pragma unroll
      for (int i = 0; i < 2; ++i)
#pragma unroll
        for (int j = 0; j < 4; ++j)
          acc[i][j] = __builtin_amdgcn_mfma_f32_16x16x32_bf16(af[i], bfr[j], acc[i][j], 0, 0, 0);
    }
    __syncthreads();
  }

  // epilogue: LDS stage (128 rows x 64 cols, pad 8) -> coalesced 16B stores
  {
    constexpr int LDC = 72;
    US* Cs = shm;                              // 128*72 = 9216 US
#pragma unroll
    for (int i = 0; i < 2; ++i)
#pragma unroll
      for (int j = 0; j < 4; ++j) {
        int colg = j * 16 + lm;
#pragma unroll
        for (int r = 0; r < 4; ++r)
          Cs[(wr + i * 16 + lk * 4 + r) * LDC + colg] = f2bf(acc[i][j][r]);
      }
    __syncthreads();
    // full row = 8 chunks of 16B; 1024 slots = 128 rows x 8 chunks.
#pragma unroll
    for (int c = 0; c < 4; ++c) {
      int idx = tid + c * 256;
      int row = idx >> 3;       // 0..127
      int ch = idx & 7;         // 0..7
      uint4 v = *(const uint4*)&Cs[row * LDC + ch * 8];
      if (bm + row < M) *(uint4*)&C[(size_t)(bm + row) * 64 + ch * 8] = v;
    }
  }
}

// ----------------- pull aggregation -----------------
// R10 redesign: agg256 was latency-bound (VALUBusy 19%, occ 72%, L2-miss traffic
// 3.78 TB/s served mostly by L3 since t=25.6MB fits L3). Fix = more misses in
// flight: (a) pair-edge uint4 gathers (16B/lane, lanes 0-31 = edge i, lanes
// 32-63 = edge i+1 -> 16 lines/load vs 8), (b) unroll 8 edges -> 4 gathers in
// flight = 64 lines/wave (vs 32), (c) 4 nodes per 256-thread block -> up to
// 32 waves/CU (single-wave WGs capped at ~72% by WG slots).

template <bool RELU>
__global__ __launch_bounds__(256) void agg256_kernel(
    const US* __restrict__ t, US* __restrict__ out,
    const int* __restrict__ row_ptr, const int* __restrict__ cnt,
    const int2* __restrict__ srcs2, const float* __restrict__ dinv,
    const float* __restrict__ bias) {
  int j = blockIdx.x * 4 + (threadIdx.x >> 6);
  int lane = threadIdx.x & 63;
  int h = lane & 31;           // dim-group: dims h*8 .. h*8+7
  int eidx = lane >> 5;        // which edge of the pair this half handles
  int base = h * 8;
  int start = row_ptr[j];
  int n = cnt[j];
  float a[8];
#pragma unroll
  for (int k = 0; k < 8; ++k) a[k] = 0.f;

  int i = 0;
  for (; i + 7 < n; i += 8) {
    int2 e0 = srcs2[start + i + 0 + eidx];
    int2 e1 = srcs2[start + i + 2 + eidx];
    int2 e2 = srcs2[start + i + 4 + eidx];
    int2 e3 = srcs2[start + i + 6 + eidx];
    uint4 v0 = *(const uint4*)(t + (size_t)e0.x * 256 + base);
    uint4 v1 = *(const uint4*)(t + (size_t)e1.x * 256 + base);
    uint4 v2 = *(const uint4*)(t + (size_t)e2.x * 256 + base);
    uint4 v3 = *(const uint4*)(t + (size_t)e3.x * 256 + base);
    float w0 = __int_as_float(e0.y), w1 = __int_as_float(e1.y);
    float w2 = __int_as_float(e2.y), w3 = __int_as_float(e3.y);
    a[0] += bflo(v0.x) * w0; a[1] += bfhi(v0.x) * w0;
    a[2] += bflo(v0.y) * w0; a[3] += bfhi(v0.y) * w0;
    a[4] += bflo(v0.z) * w0; a[5] += bfhi(v0.z) * w0;
    a[6] += bflo(v0.w) * w0; a[7] += bfhi(v0.w) * w0;
    a[0] += bflo(v1.x) * w1; a[1] += bfhi(v1.x) * w1;
    a[2] += bflo(v1.y) * w1; a[3] += bfhi(v1.y) * w1;
    a[4] += bflo(v1.z) * w1; a[5] += bfhi(v1.z) * w1;
    a[6] += bflo(v1.w) * w1; a[7] += bfhi(v1.w) * w1;
    a[0] += bflo(v2.x) * w2; a[1] += bfhi(v2.x) * w2;
    a[2] += bflo(v2.y) * w2; a[3] += bfhi(v2.y) * w2;
    a[4] += bflo(v2.z) * w2; a[5] += bfhi(v2.z) * w2;
    a[6] += bflo(v2.w) * w2; a[7] += bfhi(v2.w) * w2;
    a[0] += bflo(v3.x) * w3; a[1] += bfhi(v3.x) * w3;
    a[2] += bflo(v3.y) * w3; a[3] += bfhi(v3.y) * w3;
    a[4] += bflo(v3.z) * w3; a[5] += bfhi(v3.z) * w3;
    a[6] += bflo(v3.w) * w3; a[7] += bfhi(v3.w) * w3;
  }
  for (; i < n; i += 2) {
    int idx = i + eidx;
    int cl = min(idx, n - 1);
    int2 e = srcs2[start + cl];
    float w = (idx < n) ? __int_as_float(e.y) : 0.f;
    uint4 v = *(const uint4*)(t + (size_t)e.x * 256 + base);
    a[0] += bflo(v.x) * w; a[1] += bfhi(v.x) * w;
    a[2] += bflo(v.y) * w; a[3] += bfhi(v.y) * w;
    a[4] += bflo(v.z) * w; a[5] += bfhi(v.z) * w;
    a[6] += bflo(v.w) * w; a[7] += bfhi(v.w) * w;
  }
  // cross-half combine: lane L and L^32 hold partials for the same dims
#pragma unroll
  for (int k = 0; k < 8; ++k) a[k] += __shfl_xor(a[k], 32, 64);

  float dj = dinv[j];
  uint4 vj = *(const uint4*)(t + (size_t)j * 256 + base);
  float4 bv0 = *(const float4*)(bias + base);
  float4 bv1 = *(const float4*)(bias + base + 4);
  float r[8];
  r[0] = (a[0] + bflo(vj.x) * dj) * dj + bv0.x;
  r[1] = (a[1] + bfhi(vj.x) * dj) * dj + bv0.y;
  r[2] = (a[2] + bflo(vj.y) * dj) * dj + bv0.z;
  r[3] = (a[3] + bfhi(vj.y) * dj) * dj + bv0.w;
  r[4] = (a[4] + bflo(vj.z) * dj) * dj + bv1.x;
  r[5] = (a[5] + bfhi(vj.z) * dj) * dj + bv1.y;
  r[6] = (a[6] + bflo(vj.w) * dj) * dj + bv1.z;
  r[7] = (a[7] + bfhi(vj.w) * dj) * dj + bv1.w;
  if (RELU) {
#pragma unroll
    for (int k = 0; k < 8; ++k) r[k] = fmaxf(r[k], 0.f);
  }
  if (lane < 32) {
    US o[8];
#pragma unroll
    for (int k = 0; k < 8; ++k) o[k] = f2bf(r[k]);
    *(uint4*)(out + (size_t)j * 256 + base) = *(const uint4*)o;
  }
}

// agg64: same idea, 4 edges per uint2 load (16-lane groups), combine via 2 shuffles.
__global__ __launch_bounds__(256) void agg64_kernel(
    const US* __restrict__ t, US* __restrict__ out,
    const int* __restrict__ row_ptr, const int* __restrict__ cnt,
    const int2* __restrict__ srcs2, const float* __restrict__ dinv,
    const float* __restrict__ bias) {
  int j = blockIdx.x * 4 + (threadIdx.x >> 6);
  int lane = threadIdx.x & 63;
  int g = lane & 15;           // dims g*4 .. g*4+3
  int eidx = lane >> 4;        // 0..3: which edge of the quad
  int base = g * 4;
  int start = row_ptr[j];
  int n = cnt[j];
  float a[4] = {0.f, 0.f, 0.f, 0.f};

  int i = 0;
  for (; i + 7 < n; i += 8) {
    int2 e0 = srcs2[start + i + eidx];
    int2 e1 = srcs2[start + i + 4 + eidx];
    uint2 v0 = *(const uint2*)(t + (size_t)e0.x * 64 + base);
    uint2 v1 = *(const uint2*)(t + (size_t)e1.x * 64 + base);
    float w0 = __int_as_float(e0.y), w1 = __int_as_float(e1.y);
    a[0] += bflo(v0.x) * w0; a[1] += bfhi(v0.x) * w0;
    a[2] += bflo(v0.y) * w0; a[3] += bfhi(v0.y) * w0;
    a[0] += bflo(v1.x) * w1; a[1] += bfhi(v1.x) * w1;
    a[2] += bflo(v1.y) * w1; a[3] += bfhi(v1.y) * w1;
  }
  for (; i < n; i += 4) {
    int idx = i + eidx;
    int cl = min(idx, n - 1);
    int2 e = srcs2[start + cl];
    float w = (idx < n) ? __int_as_float(e.y) : 0.f;
    uint2 v = *(const uint2*)(t + (size_t)e.x * 64 + base);
    a[0] += bflo(v.x) * w; a[1] += bfhi(v.x) * w;
    a[2] += bflo(v.y) * w; a[3] += bfhi(v.y) * w;
  }
#pragma unroll
  for (int k = 0; k < 4; ++k) {
    a[k] += __shfl_xor(a[k], 16, 64);
    a[k] += __shfl_xor(a[k], 32, 64);
  }

  float dj = dinv[j];
  uint2 vj = *(const uint2*)(t + (size_t)j * 64 + base);
  float4 bv = *(const float4*)(bias + base);
  float r0 = (a[0] + bflo(vj.x) * dj) * dj + bv.x;
  float r1 = (a[1] + bfhi(vj.x) * dj) * dj + bv.y;
  float r2 = (a[2] + bflo(vj.y) * dj) * dj + bv.z;
  float r3 = (a[3] + bfhi(vj.y) * dj) * dj + bv.w;
  if (lane < 16) {
    unsigned int o0 = ((unsigned int)f2bf(r1) << 16) | f2bf(r0);
    unsigned int o1 = ((unsigned int)f2bf(r3) << 16) | f2bf(r2);
    *(uint2*)(out + (size_t)j * 64 + base) = make_uint2(o0, o1);
  }
}

// ----------------- final dense: sigmoid(H[N,64] @ W4t^T + b4), MFMA -----------------

__global__ __launch_bounds__(256) void final_mfma_kernel(
    const US* __restrict__ H, const US* __restrict__ W4t,
    const float* __restrict__ b4, float* __restrict__ out, int M) {
  int wv = threadIdx.x >> 6, lane = threadIdx.x & 63;
  int m0 = blockIdx.x * 64 + wv * 16;
  if (m0 >= M) return;
  int lm = lane & 15, lk = lane >> 4;

  floatx4 zero = {0.f, 0.f, 0.f, 0.f};
  floatx4 acc[4] = {zero, zero, zero, zero};
#pragma unroll
  for (int ks = 0; ks < 2; ++ks) {
    short8 af = *(const short8*)&H[(size_t)(m0 + lm) * 64 + ks * 32 + lk * 8];
#pragma unroll
    for (int jt = 0; jt < 4; ++jt) {
      short8 bf = *(const short8*)&W4t[(size_t)(jt * 16 + lm) * 64 + ks * 32 + lk * 8];
      acc[jt] = __builtin_amdgcn_mfma_f32_16x16x32_bf16(af, bf, acc[jt], 0, 0, 0);
    }
  }
#pragma unroll
  for (int jt = 0; jt < 4; ++jt) {
    int col = jt * 16 + lm;
    float bv = b4[col];
#pragma unroll
    for (int r = 0; r < 4; ++r) {
      int m = m0 + lk * 4 + r;
      float v = acc[jt][r] + bv;
      out[(size_t)m * 64 + col] = 1.0f / (1.0f + expf(-v));
    }
  }
}

// ----------------- driver -----------------

extern "C" void kernel_launch(void* const* d_in, const int* in_sizes, int n_in,
                              void* d_out, int out_size, void* d_ws, size_t ws_size,
                              hipStream_t stream) {
  const float* x  = (const float*)d_in[0];
  const int* ei   = (const int*)d_in[1];
  const float* W1 = (const float*)d_in[2];
  const float* b1 = (const float*)d_in[3];
  const float* W2 = (const float*)d_in[4];
  const float* b2 = (const float*)d_in[5];
  const float* W3 = (const float*)d_in[6];
  const float* b3 = (const float*)d_in[7];
  const float* W4 = (const float*)d_in[8];
  const float* b4 = (const float*)d_in[9];
  float* outp = (float*)d_out;

  const int N = N_NODES, E = N_EDGES;
  const int* row = ei;
  const int* col = ei + E;

  US* Ab = (US*)d_ws;                         // [N,256] bf16 ping
  US* Bb = Ab + (size_t)N * 256;              // [N,256] bf16 pong
  US* B64 = Bb + (size_t)N * 256;             // [N,64] (layer-6 GEMM out)
  US* Hfin = B64 + (size_t)N * 64;            // [N,64] (final GEMM in)
  float* dinv = (float*)(Hfin + (size_t)N * 64);
  int* cnt = (int*)(dinv + N);
  int* row_ptr = cnt + N;
  int* fill = row_ptr + N;
  int* bsums = fill + N;                      // [256]
  int2* srcs2 = (int2*)(bsums + 256);         // [E]
  US* Wt1 = (US*)(srcs2 + E);                 // [256,256]
  US* Wt2 = Wt1 + 256 * 256;
  US* Wt3 = Wt2 + 256 * 256;                  // [64,256]
  US* Wt4 = Wt3 + 64 * 256;                   // [64,64]

  hipMemsetAsync(cnt, 0, N * sizeof(int), stream);
  pre0_kernel<<<1024, 256, 0, stream>>>(col, cnt, x, Ab, W1, W2, W3, W4,
                                        Wt1, Wt2, Wt3, Wt4);
  int nblk = (N + 255) / 256;
  scan_block_kernel<<<nblk, 256, 0, stream>>>(cnt, row_ptr, bsums, dinv, N);
  scan_top_kernel<<<1, 256, 0, stream>>>(bsums, nblk);
  scan_add_kernel<<<nblk, 256, 0, stream>>>(row_ptr, fill, bsums, N);
  fill_kernel<<<(E + 255) / 256, 256, 0, stream>>>(row, col, fill, srcs2, dinv, E);

  gemm256_kernel<<<(N + 63) / 64, 256, 0, stream>>>(Ab, Wt1, Bb, N);
  agg256_kernel<true><<<N / 4, 256, 0, stream>>>(Bb, Ab, row_ptr, cnt, srcs2, dinv, b1);
  for (int l = 0; l < 4; ++l) {
    gemm256_kernel<<<(N + 63) / 64, 256, 0, stream>>>(Ab, Wt2, Bb, N);
    agg256_kernel<true><<<N / 4, 256, 0, stream>>>(Bb, Ab, row_ptr, cnt, srcs2, dinv, b2);
  }
  gemm64_kernel<<<(N + 127) / 128, 256, 0, stream>>>(Ab, Wt3, B64, N);
  agg64_kernel<<<N / 4, 256, 0, stream>>>(B64, Hfin, row_ptr, cnt, srcs2, dinv, b3);
  final_mfma_kernel<<<(N + 63) / 64, 256, 0, stream>>>(Hfin, Wt4, b4, outp, N);
}

// Round 2
// 610.053 us; speedup vs baseline: 1.0100x; 1.0100x over previous
//
#include <hip/hip_runtime.h>
#include <hip/hip_bf16.h>
#include <math.h>

#define N_NODES 50000
#define N_EDGES 800000
#define GK 256

typedef unsigned short US;
typedef __attribute__((ext_vector_type(8))) short short8;
typedef __attribute__((ext_vector_type(4))) float floatx4;
typedef __attribute__((address_space(1))) const void* gptr_t;
typedef __attribute__((address_space(3))) void* lptr_t;

static __device__ __forceinline__ float bflo(unsigned int u) {
  union { unsigned int i; float f; } c; c.i = u << 16; return c.f;
}
static __device__ __forceinline__ float bfhi(unsigned int u) {
  union { unsigned int i; float f; } c; c.i = u & 0xffff0000u; return c.f;
}
static __device__ __forceinline__ float bf2f(US u) {
  union { unsigned int i; float f; } c; c.i = ((unsigned int)u) << 16; return c.f;
}
static __device__ __forceinline__ US f2bf(float f) {  // round-to-nearest-even
  union { float f; unsigned int i; } c; c.f = f;
  unsigned int x = c.i;
  return (US)((x + 0x7fffu + ((x >> 16) & 1u)) >> 16);
}

// ----------------- preprocessing -----------------

// fused: in-degree histogram + x->bf16 + all weight transposes
__global__ void pre0_kernel(const int* __restrict__ col, int* __restrict__ cnt,
                            const float* __restrict__ x, US* __restrict__ xb,
                            const float* __restrict__ W1, const float* __restrict__ W2,
                            const float* __restrict__ W3, const float* __restrict__ W4,
                            US* __restrict__ Wt1, US* __restrict__ Wt2,
                            US* __restrict__ Wt3, US* __restrict__ Wt4) {
  int gt = blockIdx.x * 256 + threadIdx.x;
  int gs = gridDim.x * 256;
  for (int e = gt; e < N_EDGES; e += gs) atomicAdd(&cnt[col[e]], 1);
  for (int i = gt; i < N_NODES * 64; i += gs) {   // x: 12.8M elems / 4
    float4 v = *(const float4*)(x + (size_t)i * 4);
    US o[4] = { f2bf(v.x), f2bf(v.y), f2bf(v.z), f2bf(v.w) };
    *(ushort4*)(xb + (size_t)i * 4) = *(ushort4*)o;
  }
  for (int idx = gt; idx < 151552; idx += gs) {
    if (idx < 65536) {
      int k = idx >> 8, n = idx & 255;
      Wt1[n * 256 + k] = f2bf(W1[idx]);
    } else if (idx < 131072) {
      int i = idx - 65536, k = i >> 8, n = i & 255;
      Wt2[n * 256 + k] = f2bf(W2[i]);
    } else if (idx < 147456) {
      int i = idx - 131072, k = i >> 6, n = i & 63;
      Wt3[n * 256 + k] = f2bf(W3[i]);
    } else {
      int i = idx - 147456, k = i >> 6, n = i & 63;
      Wt4[n * 64 + k] = f2bf(W4[i]);
    }
  }
}

__global__ void scan_block_kernel(const int* __restrict__ in, int* __restrict__ out,
                                  int* __restrict__ bsums, float* __restrict__ dinv, int n) {
  __shared__ int s[256];
  int gid = blockIdx.x * 256 + threadIdx.x;
  int v = (gid < n) ? in[gid] : 0;
  if (gid < n) dinv[gid] = 1.0f / sqrtf((float)(v + 1));  // +1 self-loop
  s[threadIdx.x] = v;
  __syncthreads();
  for (int off = 1; off < 256; off <<= 1) {
    int t = (threadIdx.x >= off) ? s[threadIdx.x - off] : 0;
    __syncthreads();
    s[threadIdx.x] += t;
    __syncthreads();
  }
  if (gid < n) out[gid] = s[threadIdx.x] - v;  // exclusive
  if (threadIdx.x == 255) bsums[blockIdx.x] = s[255];
}

__global__ void scan_top_kernel(int* __restrict__ bsums, int n) {
  __shared__ int s[256];
  int v = (threadIdx.x < n) ? bsums[threadIdx.x] : 0;
  s[threadIdx.x] = v;
  __syncthreads();
  for (int off = 1; off < 256; off <<= 1) {
    int t = (threadIdx.x >= off) ? s[threadIdx.x - off] : 0;
    __syncthreads();
    s[threadIdx.x] += t;
    __syncthreads();
  }
  if (threadIdx.x < n) bsums[threadIdx.x] = s[threadIdx.x] - v;
}

__global__ void scan_add_kernel(int* __restrict__ row_ptr, int* __restrict__ fill,
                                const int* __restrict__ bsums, int n) {
  int gid = blockIdx.x * 256 + threadIdx.x;
  if (gid < n) {
    int v = row_ptr[gid] + bsums[blockIdx.x];
    row_ptr[gid] = v;
    fill[gid] = v;
  }
}

__global__ void fill_kernel(const int* __restrict__ row, const int* __restrict__ col,
                            int* __restrict__ fill, int2* __restrict__ srcs2,
                            const float* __restrict__ dinv, int E) {
  int e = blockIdx.x * blockDim.x + threadIdx.x;
  if (e < E) {
    int d = col[e];
    int r = row[e];
    int pos = atomicAdd(&fill[d], 1);
    srcs2[pos] = make_int2(r, __float_as_int(dinv[r]));
  }
}

// ----------------- gemm256: C[M,256] = A[M,256] @ Wt[256,256]^T -----------------
// R2: double-buffered LDS (80KB) + counted vmcnt(10) + raw s_barrier pipeline.
// The old 2-barrier loop serialized 4 full staging latencies per block
// (__syncthreads drains vmcnt(0)); now next K-tile's loads stay in flight
// across the barrier while the current tile computes.

__global__ __launch_bounds__(256) void gemm256_kernel(
    const US* __restrict__ A, const US* __restrict__ Wt,
    US* __restrict__ C, int M) {
  __shared__ __align__(16) US shm[40960];      // 80KB
  // layout: As0 [0,4096) As1 [4096,8192) Bs0 [8192,24576) Bs1 [24576,40960)
  int tid = threadIdx.x;
  int bm = blockIdx.x * 64;
  int lane = tid & 63;
  int w = tid >> 6;
  int wc = w * 64;
  int lm = lane & 15, lk = lane >> 4;
  int lr = lane >> 3, lc = lane & 7;
  int gc = lc ^ lr;

  floatx4 zero = {0.f, 0.f, 0.f, 0.f};
  floatx4 acc[4][4];
#pragma unroll
  for (int i = 0; i < 4; ++i)
#pragma unroll
    for (int j = 0; j < 4; ++j) acc[i][j] = zero;

  // issue the 10 global_load_lds for K-tile k into buffer b (unconditional: 10 exact)
  auto issue = [&](int k, int b) {
    int k0 = k * 64;
    US* As = shm + b * 4096;
    US* Bs = shm + 8192 + b * 16384;
#pragma unroll
    for (int i = 0; i < 2; ++i) {
      int rbase = i * 32 + w * 8;
      int r = min(bm + rbase + lr, M - 1);   // clamp keeps load count exact
      const US* ga = A + (size_t)r * GK + k0 + gc * 8;
      __builtin_amdgcn_global_load_lds((gptr_t)(const void*)ga,
                                       (lptr_t)(void*)&As[rbase * 64], 16, 0, 0);
    }
#pragma unroll
    for (int i = 0; i < 8; ++i) {
      int rbase = i * 32 + w * 8;
      int r = rbase + lr;
      const US* gb = Wt + (size_t)r * GK + k0 + gc * 8;
      __builtin_amdgcn_global_load_lds((gptr_t)(const void*)gb,
                                       (lptr_t)(void*)&Bs[rbase * 64], 16, 0, 0);
    }
  };

  issue(0, 0);
#pragma unroll
  for (int k = 0; k < 4; ++k) {
    if (k < 3) {
      issue(k + 1, (k + 1) & 1);
      asm volatile("s_waitcnt vmcnt(10)" ::: "memory");   // tile-k loads done, k+1 in flight
    } else {
      asm volatile("s_waitcnt vmcnt(0)" ::: "memory");
    }
    __builtin_amdgcn_sched_barrier(0);
    __builtin_amdgcn_s_barrier();            // raw: no compiler vmcnt(0) drain
    const US* As = shm + (k & 1) * 4096;
    const US* Bs = shm + 8192 + (k & 1) * 16384;
#pragma unroll
    for (int s = 0; s < 2; ++s) {
      short8 af[4], bfr[4];
#pragma unroll
      for (int i = 0; i < 4; ++i) {
        int row = i * 16 + lm;
        int c = (s * 4 + lk) ^ (row & 7);
        af[i] = *(const short8*)&As[row * 64 + c * 8];
      }
#pragma unroll
      for (int j = 0; j < 4; ++j) {
        int row = wc + j * 16 + lm;
        int c = (s * 4 + lk) ^ (row & 7);
        bfr[j] = *(const short8*)&Bs[row * 64 + c * 8];
      }
#pragma unroll
      for (int i = 0; i < 4; ++i)
#pragma unroll
        for (int j = 0; j < 4; ++j)
          acc[i][j] = __builtin_amdgcn_mfma_f32_16x16x32_bf16(af[i], bfr[j], acc[i][j], 0, 0, 0);
    }
    __builtin_amdgcn_s_barrier();            // buffer-reuse guard (ds_reads consumed by MFMA)
  }

  // epilogue: LDS stage (64 rows x 256 cols, pad 16) -> coalesced 16B stores
  {
    constexpr int LDC = 272;
    US* Cs = shm;                              // 64*272 = 17408 US <= 40960
#pragma unroll
    for (int i = 0; i < 4; ++i)
#pragma unroll
      for (int j = 0; j < 4; ++j) {
        int colg = wc + j * 16 + lm;
#pragma unroll
        for (int r = 0; r < 4; ++r)
          Cs[(i * 16 + lk * 4 + r) * LDC + colg] = f2bf(acc[i][j][r]);
      }
    __syncthreads();
#pragma unroll
    for (int c = 0; c < 8; ++c) {              // 2048 = 64 rows x 32 chunks
      int idx = tid + c * 256;
      int row = idx >> 5;
      int ch = idx & 31;
      uint4 v = *(const uint4*)&Cs[row * LDC + ch * 8];
      if (bm + row < M) *(uint4*)&C[(size_t)(bm + row) * 256 + ch * 8] = v;
    }
  }
}

// ----------------- gemm64: C[M,64] = A[M,256] @ Wt3[64,256]^T -----------------
// Same pipeline: 6 loads/unit, vmcnt(6), 48KB double-buffered LDS.

__global__ __launch_bounds__(256) void gemm64_kernel(
    const US* __restrict__ A, const US* __restrict__ Wt,
    US* __restrict__ C, int M) {
  __shared__ __align__(16) US shm[24576];      // 48KB
  // layout: As0 [0,8192) As1 [8192,16384) Bs0 [16384,20480) Bs1 [20480,24576)
  int tid = threadIdx.x;
  int bm = blockIdx.x * 128;
  int lane = tid & 63;
  int w = tid >> 6;
  int wr = w * 32;
  int lm = lane & 15, lk = lane >> 4;
  int lr = lane >> 3, lc = lane & 7;
  int gc = lc ^ lr;

  floatx4 zero = {0.f, 0.f, 0.f, 0.f};
  floatx4 acc[2][4];
#pragma unroll
  for (int i = 0; i < 2; ++i)
#pragma unroll
    for (int j = 0; j < 4; ++j) acc[i][j] = zero;

  auto issue = [&](int k, int b) {
    int k0 = k * 64;
    US* As = shm + b * 8192;
    US* Bs = shm + 16384 + b * 4096;
#pragma unroll
    for (int i = 0; i < 4; ++i) {
      int rbase = i * 32 + w * 8;
      int r = min(bm + rbase + lr, M - 1);
      const US* ga = A + (size_t)r * GK + k0 + gc * 8;
      __builtin_amdgcn_global_load_lds((gptr_t)(const void*)ga,
                                       (lptr_t)(void*)&As[rbase * 64], 16, 0, 0);
    }
#pragma unroll
    for (int i = 0; i < 2; ++i) {
      int rbase = i * 32 + w * 8;
      int r = rbase + lr;
      const US* gb = Wt + (size_t)r * GK + k0 + gc * 8;
      __builtin_amdgcn_global_load_lds((gptr_t)(const void*)gb,
                                       (lptr_t)(void*)&Bs[rbase * 64], 16, 0, 0);
    }
  };

  issue(0, 0);
#pragma unroll
  for (int k = 0; k < 4; ++k) {
    if (k < 3) {
      issue(k + 1, (k + 1) & 1);
      asm volatile("s_waitcnt vmcnt(6)" ::: "memory");
    } else {
      asm volatile("s_waitcnt vmcnt(0)" ::: "memory");
    }
    __builtin_amdgcn_sched_barrier(0);
    __builtin_amdgcn_s_barrier();
    const US* As = shm + (k & 1) * 8192;
    const US* Bs = shm + 16384 + (k & 1) * 4096;
#pragma unroll
    for (int s = 0; s < 2; ++s) {
      short8 af[2], bfr[4];
#pragma unroll
      for (int i = 0; i < 2; ++i) {
        int row = wr + i * 16 + lm;
        int c = (s * 4 + lk) ^ (row & 7);
        af[i] = *(const short8*)&As[row * 64 + c * 8];
      }
#pragma unroll
      for (int j = 0; j < 4; ++j) {
        int row = j * 16 + lm;
        int c = (s * 4 + lk) ^ (row & 7);
        bfr[j] = *(const short8*)&Bs[row * 64 + c * 8];
      }
#pragma unroll
      for (int i = 0; i < 2; ++i)
#pragma unroll
        for (int j = 0; j < 4; ++j)
          acc[i][j] = __builtin_amdgcn_mfma_f32_16x16x32_bf16(af[i], bfr[j], acc[i][j], 0, 0, 0);
    }
    __builtin_amdgcn_s_barrier();
  }

  // epilogue: LDS stage (128 rows x 64 cols, pad 8) -> coalesced 16B stores
  {
    constexpr int LDC = 72;
    US* Cs = shm;                              // 128*72 = 9216 US <= 24576
#pragma unroll
    for (int i = 0; i < 2; ++i)
#pragma unroll
      for (int j = 0; j < 4; ++j) {
        int colg = j * 16 + lm;
#pragma unroll
        for (int r = 0; r < 4; ++r)
          Cs[(wr + i * 16 + lk * 4 + r) * LDC + colg] = f2bf(acc[i][j][r]);
      }
    __syncthreads();
    // full row = 8 chunks of 16B; 1024 slots = 128 rows x 8 chunks.
#pragma unroll
    for (int c = 0; c < 4; ++c) {
      int idx = tid + c * 256;
      int row = idx >> 3;       // 0..127
      int ch = idx & 7;         // 0..7
      uint4 v = *(const uint4*)&Cs[row * LDC + ch * 8];
      if (bm + row < M) *(uint4*)&C[(size_t)(bm + row) * 64 + ch * 8] = v;
    }
  }
}

// ----------------- pull aggregation -----------------
// R1 structure kept: pair-edge uint4 gathers, 4 nodes/block. Measured
// rate-limited at ~3.7 TB/s on the L2-miss path (FETCH unchanged across
// two very different structures) -> near structural floor for random graph.

template <bool RELU>
__global__ __launch_bounds__(256) void agg256_kernel(
    const US* __restrict__ t, US* __restrict__ out,
    const int* __restrict__ row_ptr, const int* __restrict__ cnt,
    const int2* __restrict__ srcs2, const float* __restrict__ dinv,
    const float* __restrict__ bias) {
  int j = blockIdx.x * 4 + (threadIdx.x >> 6);
  int lane = threadIdx.x & 63;
  int h = lane & 31;           // dim-group: dims h*8 .. h*8+7
  int eidx = lane >> 5;        // which edge of the pair this half handles
  int base = h * 8;
  int start = row_ptr[j];
  int n = cnt[j];
  float a[8];
#pragma unroll
  for (int k = 0; k < 8; ++k) a[k] = 0.f;

  int i = 0;
  for (; i + 7 < n; i += 8) {
    int2 e0 = srcs2[start + i + 0 + eidx];
    int2 e1 = srcs2[start + i + 2 + eidx];
    int2 e2 = srcs2[start + i + 4 + eidx];
    int2 e3 = srcs2[start + i + 6 + eidx];
    uint4 v0 = *(const uint4*)(t + (size_t)e0.x * 256 + base);
    uint4 v1 = *(const uint4*)(t + (size_t)e1.x * 256 + base);
    uint4 v2 = *(const uint4*)(t + (size_t)e2.x * 256 + base);
    uint4 v3 = *(const uint4*)(t + (size_t)e3.x * 256 + base);
    float w0 = __int_as_float(e0.y), w1 = __int_as_float(e1.y);
    float w2 = __int_as_float(e2.y), w3 = __int_as_float(e3.y);
    a[0] += bflo(v0.x) * w0; a[1] += bfhi(v0.x) * w0;
    a[2] += bflo(v0.y) * w0; a[3] += bfhi(v0.y) * w0;
    a[4] += bflo(v0.z) * w0; a[5] += bfhi(v0.z) * w0;
    a[6] += bflo(v0.w) * w0; a[7] += bfhi(v0.w) * w0;
    a[0] += bflo(v1.x) * w1; a[1] += bfhi(v1.x) * w1;
    a[2] += bflo(v1.y) * w1; a[3] += bfhi(v1.y) * w1;
    a[4] += bflo(v1.z) * w1; a[5] += bfhi(v1.z) * w1;
    a[6] += bflo(v1.w) * w1; a[7] += bfhi(v1.w) * w1;
    a[0] += bflo(v2.x) * w2; a[1] += bfhi(v2.x) * w2;
    a[2] += bflo(v2.y) * w2; a[3] += bfhi(v2.y) * w2;
    a[4] += bflo(v2.z) * w2; a[5] += bfhi(v2.z) * w2;
    a[6] += bflo(v2.w) * w2; a[7] += bfhi(v2.w) * w2;
    a[0] += bflo(v3.x) * w3; a[1] += bfhi(v3.x) * w3;
    a[2] += bflo(v3.y) * w3; a[3] += bfhi(v3.y) * w3;
    a[4] += bflo(v3.z) * w3; a[5] += bfhi(v3.z) * w3;
    a[6] += bflo(v3.w) * w3; a[7] += bfhi(v3.w) * w3;
  }
  for (; i < n; i += 2) {
    int idx = i + eidx;
    int cl = min(idx, n - 1);
    int2 e = srcs2[start + cl];
    float w = (idx < n) ? __int_as_float(e.y) : 0.f;
    uint4 v = *(const uint4*)(t + (size_t)e.x * 256 + base);
    a[0] += bflo(v.x) * w; a[1] += bfhi(v.x) * w;
    a[2] += bflo(v.y) * w; a[3] += bfhi(v.y) * w;
    a[4] += bflo(v.z) * w; a[5] += bfhi(v.z) * w;
    a[6] += bflo(v.w) * w; a[7] += bfhi(v.w) * w;
  }
  // cross-half combine: lane L and L^32 hold partials for the same dims
#pragma unroll
  for (int k = 0; k < 8; ++k) a[k] += __shfl_xor(a[k], 32, 64);

  float dj = dinv[j];
  uint4 vj = *(const uint4*)(t + (size_t)j * 256 + base);
  float4 bv0 = *(const float4*)(bias + base);
  float4 bv1 = *(const float4*)(bias + base + 4);
  float r[8];
  r[0] = (a[0] + bflo(vj.x) * dj) * dj + bv0.x;
  r[1] = (a[1] + bfhi(vj.x) * dj) * dj + bv0.y;
  r[2] = (a[2] + bflo(vj.y) * dj) * dj + bv0.z;
  r[3] = (a[3] + bfhi(vj.y) * dj) * dj + bv0.w;
  r[4] = (a[4] + bflo(vj.z) * dj) * dj + bv1.x;
  r[5] = (a[5] + bfhi(vj.z) * dj) * dj + bv1.y;
  r[6] = (a[6] + bflo(vj.w) * dj) * dj + bv1.z;
  r[7] = (a[7] + bfhi(vj.w) * dj) * dj + bv1.w;
  if (RELU) {
#pragma unroll
    for (int k = 0; k < 8; ++k) r[k] = fmaxf(r[k], 0.f);
  }
  if (lane < 32) {
    US o[8];
#pragma unroll
    for (int k = 0; k < 8; ++k) o[k] = f2bf(r[k]);
    *(uint4*)(out + (size_t)j * 256 + base) = *(const uint4*)o;
  }
}

// agg64: same idea, 4 edges per uint2 load (16-lane groups), combine via 2 shuffles.
__global__ __launch_bounds__(256) void agg64_kernel(
    const US* __restrict__ t, US* __restrict__ out,
    const int* __restrict__ row_ptr, const int* __restrict__ cnt,
    const int2* __restrict__ srcs2, const float* __restrict__ dinv,
    const float* __restrict__ bias) {
  int j = blockIdx.x * 4 + (threadIdx.x >> 6);
  int lane = threadIdx.x & 63;
  int g = lane & 15;           // dims g*4 .. g*4+3
  int eidx = lane >> 4;        // 0..3: which edge of the quad
  int base = g * 4;
  int start = row_ptr[j];
  int n = cnt[j];
  float a[4] = {0.f, 0.f, 0.f, 0.f};

  int i = 0;
  for (; i + 7 < n; i += 8) {
    int2 e0 = srcs2[start + i + eidx];
    int2 e1 = srcs2[start + i + 4 + eidx];
    uint2 v0 = *(const uint2*)(t + (size_t)e0.x * 64 + base);
    uint2 v1 = *(const uint2*)(t + (size_t)e1.x * 64 + base);
    float w0 = __int_as_float(e0.y), w1 = __int_as_float(e1.y);
    a[0] += bflo(v0.x) * w0; a[1] += bfhi(v0.x) * w0;
    a[2] += bflo(v0.y) * w0; a[3] += bfhi(v0.y) * w0;
    a[0] += bflo(v1.x) * w1; a[1] += bfhi(v1.x) * w1;
    a[2] += bflo(v1.y) * w1; a[3] += bfhi(v1.y) * w1;
  }
  for (; i < n; i += 4) {
    int idx = i + eidx;
    int cl = min(idx, n - 1);
    int2 e = srcs2[start + cl];
    float w = (idx < n) ? __int_as_float(e.y) : 0.f;
    uint2 v = *(const uint2*)(t + (size_t)e.x * 64 + base);
    a[0] += bflo(v.x) * w; a[1] += bfhi(v.x) * w;
    a[2] += bflo(v.y) * w; a[3] += bfhi(v.y) * w;
  }
#pragma unroll
  for (int k = 0; k < 4; ++k) {
    a[k] += __shfl_xor(a[k], 16, 64);
    a[k] += __shfl_xor(a[k], 32, 64);
  }

  float dj = dinv[j];
  uint2 vj = *(const uint2*)(t + (size_t)j * 64 + base);
  float4 bv = *(const float4*)(bias + base);
  float r0 = (a[0] + bflo(vj.x) * dj) * dj + bv.x;
  float r1 = (a[1] + bfhi(vj.x) * dj) * dj + bv.y;
  float r2 = (a[2] + bflo(vj.y) * dj) * dj + bv.z;
  float r3 = (a[3] + bfhi(vj.y) * dj) * dj + bv.w;
  if (lane < 16) {
    unsigned int o0 = ((unsigned int)f2bf(r1) << 16) | f2bf(r0);
    unsigned int o1 = ((unsigned int)f2bf(r3) << 16) | f2bf(r2);
    *(uint2*)(out + (size_t)j * 64 + base) = make_uint2(o0, o1);
  }
}

// ----------------- final dense: sigmoid(H[N,64] @ W4t^T + b4), MFMA -----------------

__global__ __launch_bounds__(256) void final_mfma_kernel(
    const US* __restrict__ H, const US* __restrict__ W4t,
    const float* __restrict__ b4, float* __restrict__ out, int M) {
  int wv = threadIdx.x >> 6, lane = threadIdx.x & 63;
  int m0 = blockIdx.x * 64 + wv * 16;
  if (m0 >= M) return;
  int lm = lane & 15, lk = lane >> 4;

  floatx4 zero = {0.f, 0.f, 0.f, 0.f};
  floatx4 acc[4] = {zero, zero, zero, zero};
#pragma unroll
  for (int ks = 0; ks < 2; ++ks) {
    short8 af = *(const short8*)&H[(size_t)(m0 + lm) * 64 + ks * 32 + lk * 8];
#pragma unroll
    for (int jt = 0; jt < 4; ++jt) {
      short8 bf = *(const short8*)&W4t[(size_t)(jt * 16 + lm) * 64 + ks * 32 + lk * 8];
      acc[jt] = __builtin_amdgcn_mfma_f32_16x16x32_bf16(af, bf, acc[jt], 0, 0, 0);
    }
  }
#pragma unroll
  for (int jt = 0; jt < 4; ++jt) {
    int col = jt * 16 + lm;
    float bv = b4[col];
#pragma unroll
    for (int r = 0; r < 4; ++r) {
      int m = m0 + lk * 4 + r;
      float v = acc[jt][r] + bv;
      out[(size_t)m * 64 + col] = 1.0f / (1.0f + expf(-v));
    }
  }
}

// ----------------- driver -----------------

extern "C" void kernel_launch(void* const* d_in, const int* in_sizes, int n_in,
                              void* d_out, int out_size, void* d_ws, size_t ws_size,
                              hipStream_t stream) {
  const float* x  = (const float*)d_in[0];
  const int* ei   = (const int*)d_in[1];
  const float* W1 = (const float*)d_in[2];
  const float* b1 = (const float*)d_in[3];
  const float* W2 = (const float*)d_in[4];
  const float* b2 = (const float*)d_in[5];
  const float* W3 = (const float*)d_in[6];
  const float* b3 = (const float*)d_in[7];
  const float* W4 = (const float*)d_in[8];
  const float* b4 = (const float*)d_in[9];
  float* outp = (float*)d_out;

  const int N = N_NODES, E = N_EDGES;
  const int* row = ei;
  const int* col = ei + E;

  US* Ab = (US*)d_ws;                         // [N,256] bf16 ping
  US* Bb = Ab + (size_t)N * 256;              // [N,256] bf16 pong
  US* B64 = Bb + (size_t)N * 256;             // [N,64] (layer-6 GEMM out)
  US* Hfin = B64 + (size_t)N * 64;            // [N,64] (final GEMM in)
  float* dinv = (float*)(Hfin + (size_t)N * 64);
  int* cnt = (int*)(dinv + N);
  int* row_ptr = cnt + N;
  int* fill = row_ptr + N;
  int* bsums = fill + N;                      // [256]
  int2* srcs2 = (int2*)(bsums + 256);         // [E]
  US* Wt1 = (US*)(srcs2 + E);                 // [256,256]
  US* Wt2 = Wt1 + 256 * 256;
  US* Wt3 = Wt2 + 256 * 256;                  // [64,256]
  US* Wt4 = Wt3 + 64 * 256;                   // [64,64]

  hipMemsetAsync(cnt, 0, N * sizeof(int), stream);
  pre0_kernel<<<1024, 256, 0, stream>>>(col, cnt, x, Ab, W1, W2, W3, W4,
                                        Wt1, Wt2, Wt3, Wt4);
  int nblk = (N + 255) / 256;
  scan_block_kernel<<<nblk, 256, 0, stream>>>(cnt, row_ptr, bsums, dinv, N);
  scan_top_kernel<<<1, 256, 0, stream>>>(bsums, nblk);
  scan_add_kernel<<<nblk, 256, 0, stream>>>(row_ptr, fill, bsums, N);
  fill_kernel<<<(E + 255) / 256, 256, 0, stream>>>(row, col, fill, srcs2, dinv, E);

  gemm256_kernel<<<(N + 63) / 64, 256, 0, stream>>>(Ab, Wt1, Bb, N);
  agg256_kernel<true><<<N / 4, 256, 0, stream>>>(Bb, Ab, row_ptr, cnt, srcs2, dinv, b1);
  for (int l = 0; l < 4; ++l) {
    gemm256_kernel<<<(N + 63) / 64, 256, 0, stream>>>(Ab, Wt2, Bb, N);
    agg256_kernel<true><<<N / 4, 256, 0, stream>>>(Bb, Ab, row_ptr, cnt, srcs2, dinv, b2);
  }
  gemm64_kernel<<<(N + 127) / 128, 256, 0, stream>>>(Ab, Wt3, B64, N);
  agg64_kernel<<<N / 4, 256, 0, stream>>>(B64, Hfin, row_ptr, cnt, srcs2, dinv, b3);
  final_mfma_kernel<<<(N + 63) / 64, 256, 0, stream>>>(Hfin, Wt4, b4, outp, N);
}